// Round 1
// baseline (578.736 us; speedup 1.0000x reference)
//
#include <hip/hip_runtime.h>
#include <cstdint>
#include <cstddef>

// Problem constants (B=2, S=1024, HID=4096, NH=64, NKV=8, HD=64, G=8)
#define S_LEN   1024
#define HIDDIM  4096
#define NHEADS  64
#define NKVH    8
#define HEADD   64
#define QKVN    5120          // NKV*(G+2)*HD
#define MTOK    2048          // B*S
#define INV_NORM 0.125f       // 1/sqrt(64)

typedef __bf16  bf16x8 __attribute__((ext_vector_type(8)));
typedef float   f32x4  __attribute__((ext_vector_type(4)));

__device__ __forceinline__ unsigned short f2bf(float f) {
  union { float f; unsigned u; } x; x.f = f;
  unsigned r = x.u + 0x7fffu + ((x.u >> 16) & 1u);   // RNE
  return (unsigned short)(r >> 16);
}

// async global->LDS, 16B per lane. LDS dest must be wave-uniform base + lane*16.
__device__ __forceinline__ void gload16(const void* g, void* l) {
  __builtin_amdgcn_global_load_lds(
      (const __attribute__((address_space(1))) unsigned*)g,
      (__attribute__((address_space(3))) unsigned*)l, 16, 0, 0);
}

// ---------------------------------------------------------------- converts
__global__ __launch_bounds__(256) void cvt_bf16(const float* __restrict__ in,
                                                unsigned short* __restrict__ out,
                                                int n4) {
  int stride = gridDim.x * 256;
  for (int i = blockIdx.x * 256 + threadIdx.x; i < n4; i += stride) {
    float4 v = ((const float4*)in)[i];
    ushort4 o;
    o.x = f2bf(v.x); o.y = f2bf(v.y); o.z = f2bf(v.z); o.w = f2bf(v.w);
    ((ushort4*)out)[i] = o;
  }
}

// ---------------------------------------------------------------- RoPE table
__global__ __launch_bounds__(256) void rope_table(float* __restrict__ cosT,
                                                  float* __restrict__ sinT) {
  int i = blockIdx.x * 256 + threadIdx.x;   // S*32
  int s = i >> 5, d = i & 31;
  float inv_freq = powf(10000.f, -(float)d * (1.f / 32.f));
  float ang = (float)s * inv_freq;
  cosT[i] = cosf(ang);
  sinT[i] = sinf(ang);
}

// ------------------------------------------------- RoPE + GQA scatter (q,k)
// fused: [B,S,NKV,10,HD] fp32.  Qb: [B*NH,S,HD] bf16.  Kb: [B*NKV,S,HD] bf16.
__global__ __launch_bounds__(256) void rope_qk(const float* __restrict__ fused,
                                               const float* __restrict__ cosT,
                                               const float* __restrict__ sinT,
                                               unsigned short* __restrict__ Qb,
                                               unsigned short* __restrict__ Kb) {
  int idx = blockIdx.x * 256 + threadIdx.x;  // ((bs*8+kv)*9+slot)*32+d
  int d    = idx & 31;
  int tmp  = idx >> 5;
  int slot = tmp % 9;  tmp /= 9;
  int kv   = tmp & 7;
  int bs   = tmp >> 3;
  int s    = bs & (S_LEN - 1);
  int b    = bs >> 10;

  const float* src = fused + (size_t)bs * QKVN + (kv * 10 + slot) * HEADD;
  float x0 = src[d], x1 = src[d + 32];
  float c  = cosT[s * 32 + d];
  float sn = sinT[s * 32 + d];
  float o0 = x0 * c - x1 * sn;     // out[d]    = x[d]*cos - x[d+32]*sin
  float o1 = x1 * c + x0 * sn;     // out[d+32] = x[d+32]*cos + x[d]*sin

  if (slot < 8) {
    int h = kv * 8 + slot;
    size_t base = (((size_t)(b * NHEADS + h)) * S_LEN + s) * HEADD;
    Qb[base + d]      = f2bf(o0);
    Qb[base + d + 32] = f2bf(o1);
  } else {
    size_t base = (((size_t)(b * NKVH + kv)) * S_LEN + s) * HEADD;
    Kb[base + d]      = f2bf(o0);
    Kb[base + d + 32] = f2bf(o1);
  }
}

// --------------------------------------------------------- V transpose
// fused v-slot [B,S,NKV,slot9,HD] fp32 -> Vt [B*NKV, HD, S] bf16
__global__ __launch_bounds__(256) void v_transpose(const float* __restrict__ fused,
                                                   unsigned short* __restrict__ Vt) {
  __shared__ float tile[64][65];
  int st = blockIdx.x;            // s tile
  int bk = blockIdx.y;            // b*NKV+kv
  const float* src = fused + ((size_t)(bk >> 3) * S_LEN + st * 64) * QKVN
                   + ((bk & 7) * 10 + 9) * HEADD;
  #pragma unroll
  for (int i = 0; i < 16; ++i) {
    int idx = i * 256 + threadIdx.x;
    int r = idx >> 6, d = idx & 63;
    tile[r][d] = src[(size_t)r * QKVN + d];
  }
  __syncthreads();
  unsigned short* dst = Vt + (size_t)bk * 64 * S_LEN + st * 64;
  #pragma unroll
  for (int i = 0; i < 16; ++i) {
    int idx = i * 256 + threadIdx.x;
    int d = idx >> 6, s = idx & 63;
    dst[(size_t)d * S_LEN + s] = f2bf(tile[s][d]);
  }
}

// ---------------------------------------------------------------- GEMM (NT)
// C[M][N] fp32 = A[M][K](bf16) * B[N][K](bf16)^T.  128x128 tile, BK=64,
// 4 waves (2x2), global_load_lds + XOR swizzle (linear LDS dest, inverse-
// swizzled global source, swizzled ds_read) -> conflict-free ds_read_b128.
__global__ __launch_bounds__(256) void gemm_nt(const unsigned short* __restrict__ A,
                                               const unsigned short* __restrict__ Bm,
                                               float* __restrict__ C,
                                               int M, int N, int K) {
  __shared__ unsigned short lA[128 * 64];
  __shared__ unsigned short lB[128 * 64];
  const int t    = threadIdx.x;
  const int lane = t & 63;
  const int w    = t >> 6;
  const int wr   = w >> 1, wc = w & 1;
  const int l15  = lane & 15, l4 = lane >> 4;
  const int m0   = blockIdx.y * 128;
  const int n0   = blockIdx.x * 128;

  f32x4 acc[4][4];
  #pragma unroll
  for (int mi = 0; mi < 4; ++mi)
    #pragma unroll
    for (int ni = 0; ni < 4; ++ni) acc[mi][ni] = (f32x4){0.f, 0.f, 0.f, 0.f};

  for (int k0 = 0; k0 < K; k0 += 64) {
    #pragma unroll
    for (int i = 0; i < 4; ++i) {          // 128 rows x 128B = 1024 chunks
      int c   = i * 256 + t;
      int row = c >> 3;
      int kb  = ((c & 7) * 16) ^ ((row & 7) << 4);   // inverse-swizzled source
      gload16(A  + (size_t)(m0 + row) * K + k0 + (kb >> 1), (char*)lA + c * 16);
      gload16(Bm + (size_t)(n0 + row) * K + k0 + (kb >> 1), (char*)lB + c * 16);
    }
    __syncthreads();

    #pragma unroll
    for (int kk = 0; kk < 2; ++kk) {
      bf16x8 aF[4], bF[4];
      #pragma unroll
      for (int mi = 0; mi < 4; ++mi) {
        int row = wr * 64 + mi * 16 + l15;
        int kb  = (kk * 64 + l4 * 16) ^ ((row & 7) << 4);
        aF[mi] = *(const bf16x8*)((const char*)lA + row * 128 + kb);
      }
      #pragma unroll
      for (int ni = 0; ni < 4; ++ni) {
        int row = wc * 64 + ni * 16 + l15;
        int kb  = (kk * 64 + l4 * 16) ^ ((row & 7) << 4);
        bF[ni] = *(const bf16x8*)((const char*)lB + row * 128 + kb);
      }
      #pragma unroll
      for (int mi = 0; mi < 4; ++mi)
        #pragma unroll
        for (int ni = 0; ni < 4; ++ni)
          acc[mi][ni] = __builtin_amdgcn_mfma_f32_16x16x32_bf16(
              aF[mi], bF[ni], acc[mi][ni], 0, 0, 0);
    }
    __syncthreads();
  }

  // epilogue: C/D layout col=lane&15, row=(lane>>4)*4+reg
  #pragma unroll
  for (int mi = 0; mi < 4; ++mi) {
    int r0 = m0 + wr * 64 + mi * 16 + l4 * 4;
    #pragma unroll
    for (int ni = 0; ni < 4; ++ni) {
      int c0 = n0 + wc * 64 + ni * 16 + l15;
      #pragma unroll
      for (int r = 0; r < 4; ++r)
        C[(size_t)(r0 + r) * N + c0] = acc[mi][ni][r];
    }
  }
}

// ---------------------------------------------------------------- attention
// One block per (q-tile of 64, b*NH+h). 4 waves, each owns 16 q rows.
// Causal (kt<=qt), alibi added pre-scale, online softmax, P via swizzled LDS.
__global__ __launch_bounds__(256) void attn_fwd(const unsigned short* __restrict__ Qb,
                                                const unsigned short* __restrict__ Kb,
                                                const unsigned short* __restrict__ Vt,
                                                const float* __restrict__ alibi,
                                                unsigned short* __restrict__ ctx) {
  __shared__ unsigned short lQ[64 * 64];
  __shared__ unsigned short lK[64 * 64];
  __shared__ unsigned short lV[64 * 64];
  __shared__ unsigned short lP[64 * 64];

  const int qt  = blockIdx.x;
  const int bh  = blockIdx.y;          // b*NH + h
  const int b   = bh >> 6;
  const int h   = bh & 63;
  const int kvh = b * NKVH + (h >> 3);

  const int t    = threadIdx.x;
  const int lane = t & 63;
  const int w    = t >> 6;
  const int l15  = lane & 15, l4 = lane >> 4;

  const unsigned short* Qsrc = Qb + ((size_t)bh * S_LEN + qt * 64) * HEADD;
  const unsigned short* Ksrc = Kb + (size_t)kvh * S_LEN * HEADD;
  const unsigned short* Vsrc = Vt + (size_t)kvh * 64 * S_LEN;
  const float* al = alibi + (size_t)bh * S_LEN;

  // stage Q (64 rows x 128B)
  #pragma unroll
  for (int i = 0; i < 2; ++i) {
    int c = i * 256 + t;
    int row = c >> 3;
    int kb  = ((c & 7) * 16) ^ ((row & 7) << 4);
    gload16(Qsrc + (size_t)row * HEADD + (kb >> 1), (char*)lQ + c * 16);
  }

  float mrun[4], lrun[4];
  f32x4 accO[4];
  #pragma unroll
  for (int r = 0; r < 4; ++r) { mrun[r] = -1e30f; lrun[r] = 0.f; }
  #pragma unroll
  for (int ni = 0; ni < 4; ++ni) accO[ni] = (f32x4){0.f, 0.f, 0.f, 0.f};

  for (int kt = 0; kt <= qt; ++kt) {
    #pragma unroll
    for (int i = 0; i < 2; ++i) {
      int c = i * 256 + t;
      int row = c >> 3;
      int kb  = ((c & 7) * 16) ^ ((row & 7) << 4);
      gload16(Ksrc + ((size_t)(kt * 64 + row)) * HEADD + (kb >> 1), (char*)lK + c * 16);
      gload16(Vsrc + (size_t)row * S_LEN + kt * 64 + (kb >> 1),     (char*)lV + c * 16);
    }
    __syncthreads();

    // ---- S = Q K^T  (wave w: rows w*16..+15, all 64 cols)
    f32x4 accS[4];
    #pragma unroll
    for (int ni = 0; ni < 4; ++ni) accS[ni] = (f32x4){0.f, 0.f, 0.f, 0.f};
    const int qrow_l = w * 16 + l15;
    #pragma unroll
    for (int kk = 0; kk < 2; ++kk) {
      bf16x8 qF = *(const bf16x8*)((const char*)lQ + qrow_l * 128 +
                   ((kk * 64 + l4 * 16) ^ ((qrow_l & 7) << 4)));
      #pragma unroll
      for (int ni = 0; ni < 4; ++ni) {
        int krow = ni * 16 + l15;
        bf16x8 kF = *(const bf16x8*)((const char*)lK + krow * 128 +
                     ((kk * 64 + l4 * 16) ^ ((krow & 7) << 4)));
        accS[ni] = __builtin_amdgcn_mfma_f32_16x16x32_bf16(qF, kF, accS[ni], 0, 0, 0);
      }
    }

    // ---- online softmax. Lane holds rows q0..q0+3 (C layout), cols l15+16*ni.
    const int q0 = qt * 64 + w * 16 + l4 * 4;
    float lv[4][4];
    float mt[4] = {-3e30f, -3e30f, -3e30f, -3e30f};
    #pragma unroll
    for (int ni = 0; ni < 4; ++ni) {
      int kc = kt * 64 + ni * 16 + l15;
      float ab = al[kc];
      #pragma unroll
      for (int r = 0; r < 4; ++r) {
        float x = (accS[ni][r] + ab) * INV_NORM;   // mask added after scale in ref
        x = (kc > q0 + r) ? -1e9f : x;
        lv[ni][r] = x;
        mt[r] = fmaxf(mt[r], x);
      }
    }
    #pragma unroll
    for (int off = 1; off < 16; off <<= 1)
      #pragma unroll
      for (int r = 0; r < 4; ++r)
        mt[r] = fmaxf(mt[r], __shfl_xor(mt[r], off));

    float scale[4];
    #pragma unroll
    for (int r = 0; r < 4; ++r) {
      float mn = fmaxf(mrun[r], mt[r]);
      scale[r] = __expf(mrun[r] - mn);
      mrun[r]  = mn;
    }
    float ps[4] = {0.f, 0.f, 0.f, 0.f};
    const int prow0 = w * 16 + l4 * 4;
    #pragma unroll
    for (int ni = 0; ni < 4; ++ni) {
      #pragma unroll
      for (int r = 0; r < 4; ++r) {
        float pv = __expf(lv[ni][r] - mrun[r]);
        ps[r] += pv;
        int prow = prow0 + r;
        int pb   = ((ni * 16 + l15) * 2) ^ ((prow & 7) << 4);
        *(unsigned short*)((char*)lP + prow * 128 + pb) = f2bf(pv);
      }
    }
    #pragma unroll
    for (int off = 1; off < 16; off <<= 1)
      #pragma unroll
      for (int r = 0; r < 4; ++r)
        ps[r] += __shfl_xor(ps[r], off);
    #pragma unroll
    for (int r = 0; r < 4; ++r) lrun[r] = lrun[r] * scale[r] + ps[r];
    #pragma unroll
    for (int ni = 0; ni < 4; ++ni)
      #pragma unroll
      for (int r = 0; r < 4; ++r) accO[ni][r] *= scale[r];

    __syncthreads();   // lP visible (own-wave anyway) + all waves done with lK

    // ---- O += P V   (A-frag from lP rows w*16.., B-frag from lV rows=d)
    #pragma unroll
    for (int kk = 0; kk < 2; ++kk) {
      bf16x8 pF = *(const bf16x8*)((const char*)lP + qrow_l * 128 +
                   ((kk * 64 + l4 * 16) ^ ((qrow_l & 7) << 4)));
      #pragma unroll
      for (int ni = 0; ni < 4; ++ni) {
        int vrow = ni * 16 + l15;
        bf16x8 vF = *(const bf16x8*)((const char*)lV + vrow * 128 +
                     ((kk * 64 + l4 * 16) ^ ((vrow & 7) << 4)));
        accO[ni] = __builtin_amdgcn_mfma_f32_16x16x32_bf16(pF, vF, accO[ni], 0, 0, 0);
      }
    }
    __syncthreads();   // all reads of lK/lV/lP done before next stage
  }

  // epilogue: ctx[b, q, h*64 + d] bf16
  #pragma unroll
  for (int ni = 0; ni < 4; ++ni) {
    #pragma unroll
    for (int r = 0; r < 4; ++r) {
      int q = qt * 64 + w * 16 + l4 * 4 + r;
      float o = accO[ni][r] / lrun[r];
      ctx[((size_t)b * S_LEN + q) * (NHEADS * HEADD) + h * 64 + ni * 16 + l15] = f2bf(o);
    }
  }
}

// ---------------------------------------------------------------- launch
extern "C" void kernel_launch(void* const* d_in, const int* in_sizes, int n_in,
                              void* d_out, int out_size, void* d_ws, size_t ws_size,
                              hipStream_t stream) {
  const float* hidden = (const float*)d_in[0];
  const float* alibi  = (const float*)d_in[1];
  // d_in[2] = attention_mask: deterministically causal triu(k=1) -> applied analytically
  const float* Wqkv   = (const float*)d_in[3];
  const float* Wdense = (const float*)d_in[4];
  float* out = (float*)d_out;

  char* p = (char*)d_ws;
  auto alloc = [&](size_t bytes) {
    char* r = p; p += (bytes + 255) & ~(size_t)255; return r;
  };
  unsigned short* hiddenB = (unsigned short*)alloc((size_t)MTOK * HIDDIM * 2);
  unsigned short* WqkvB   = (unsigned short*)alloc((size_t)QKVN * HIDDIM * 2);
  unsigned short* WdenseB = (unsigned short*)alloc((size_t)HIDDIM * HIDDIM * 2);
  float*          fused   = (float*)alloc((size_t)MTOK * QKVN * 4);
  unsigned short* Qb      = (unsigned short*)alloc((size_t)2 * NHEADS * S_LEN * HEADD * 2);
  unsigned short* Kb      = (unsigned short*)alloc((size_t)2 * NKVH * S_LEN * HEADD * 2);
  unsigned short* Vt      = (unsigned short*)alloc((size_t)2 * NKVH * HEADD * S_LEN * 2);
  unsigned short* ctxB    = (unsigned short*)alloc((size_t)MTOK * HIDDIM * 2);
  float*          cosT    = (float*)alloc((size_t)S_LEN * 32 * 4);
  float*          sinT    = (float*)alloc((size_t)S_LEN * 32 * 4);
  // total ~164.3 MiB of d_ws

  cvt_bf16<<<1024, 256, 0, stream>>>(hidden, hiddenB, MTOK * HIDDIM / 4);
  cvt_bf16<<<2048, 256, 0, stream>>>(Wqkv,   WqkvB,   QKVN * HIDDIM / 4);
  cvt_bf16<<<2048, 256, 0, stream>>>(Wdense, WdenseB, HIDDIM * HIDDIM / 4);
  rope_table<<<(S_LEN * 32) / 256, 256, 0, stream>>>(cosT, sinT);

  gemm_nt<<<dim3(QKVN / 128, MTOK / 128), 256, 0, stream>>>(
      hiddenB, WqkvB, fused, MTOK, QKVN, HIDDIM);

  rope_qk<<<(MTOK * NKVH * 9 * 32) / 256, 256, 0, stream>>>(fused, cosT, sinT, Qb, Kb);
  v_transpose<<<dim3(S_LEN / 64, 2 * NKVH), 256, 0, stream>>>(fused, Vt);

  attn_fwd<<<dim3(S_LEN / 64, 2 * NHEADS), 256, 0, stream>>>(Qb, Kb, Vt, alibi, ctxB);

  gemm_nt<<<dim3(HIDDIM / 128, MTOK / 128), 256, 0, stream>>>(
      ctxB, WdenseB, out, MTOK, HIDDIM, HIDDIM);
}

// Round 2
// 537.130 us; speedup vs baseline: 1.0775x; 1.0775x over previous
//
#include <hip/hip_runtime.h>
#include <cstdint>
#include <cstddef>

// Problem constants (B=2, S=1024, HID=4096, NH=64, NKV=8, HD=64, G=8)
#define S_LEN   1024
#define HIDDIM  4096
#define NHEADS  64
#define NKVH    8
#define HEADD   64
#define QKVN    5120          // NKV*(G+2)*HD
#define MTOK    2048          // B*S
#define INV_NORM 0.125f       // 1/sqrt(64)

typedef __bf16  bf16x8 __attribute__((ext_vector_type(8)));
typedef float   f32x4  __attribute__((ext_vector_type(4)));

__device__ __forceinline__ unsigned short f2bf(float f) {
  union { float f; unsigned u; } x; x.f = f;
  unsigned r = x.u + 0x7fffu + ((x.u >> 16) & 1u);   // RNE
  return (unsigned short)(r >> 16);
}

// async global->LDS, 16B per lane. LDS dest must be wave-uniform base + lane*16.
__device__ __forceinline__ void gload16(const void* g, void* l) {
  __builtin_amdgcn_global_load_lds(
      (const __attribute__((address_space(1))) unsigned*)g,
      (__attribute__((address_space(3))) unsigned*)l, 16, 0, 0);
}

// ---------------------------------------------------------------- converts
__global__ __launch_bounds__(256) void cvt_bf16(const float* __restrict__ in,
                                                unsigned short* __restrict__ out,
                                                int n4) {
  int stride = gridDim.x * 256;
  for (int i = blockIdx.x * 256 + threadIdx.x; i < n4; i += stride) {
    float4 v = ((const float4*)in)[i];
    ushort4 o;
    o.x = f2bf(v.x); o.y = f2bf(v.y); o.z = f2bf(v.z); o.w = f2bf(v.w);
    ((ushort4*)out)[i] = o;
  }
}

// ---------------------------------------------------------------- RoPE table
__global__ __launch_bounds__(256) void rope_table(float* __restrict__ cosT,
                                                  float* __restrict__ sinT) {
  int i = blockIdx.x * 256 + threadIdx.x;   // S*32
  int s = i >> 5, d = i & 31;
  float inv_freq = powf(10000.f, -(float)d * (1.f / 32.f));
  float ang = (float)s * inv_freq;
  cosT[i] = cosf(ang);
  sinT[i] = sinf(ang);
}

// ------------------------------------------------- RoPE + GQA scatter (q,k)
__global__ __launch_bounds__(256) void rope_qk(const float* __restrict__ fused,
                                               const float* __restrict__ cosT,
                                               const float* __restrict__ sinT,
                                               unsigned short* __restrict__ Qb,
                                               unsigned short* __restrict__ Kb) {
  int idx = blockIdx.x * 256 + threadIdx.x;  // ((bs*8+kv)*9+slot)*32+d
  int d    = idx & 31;
  int tmp  = idx >> 5;
  int slot = tmp % 9;  tmp /= 9;
  int kv   = tmp & 7;
  int bs   = tmp >> 3;
  int s    = bs & (S_LEN - 1);
  int b    = bs >> 10;

  const float* src = fused + (size_t)bs * QKVN + (kv * 10 + slot) * HEADD;
  float x0 = src[d], x1 = src[d + 32];
  float c  = cosT[s * 32 + d];
  float sn = sinT[s * 32 + d];
  float o0 = x0 * c - x1 * sn;
  float o1 = x1 * c + x0 * sn;

  if (slot < 8) {
    int h = kv * 8 + slot;
    size_t base = (((size_t)(b * NHEADS + h)) * S_LEN + s) * HEADD;
    Qb[base + d]      = f2bf(o0);
    Qb[base + d + 32] = f2bf(o1);
  } else {
    size_t base = (((size_t)(b * NKVH + kv)) * S_LEN + s) * HEADD;
    Kb[base + d]      = f2bf(o0);
    Kb[base + d + 32] = f2bf(o1);
  }
}

// --------------------------------------------------------- V transpose
__global__ __launch_bounds__(256) void v_transpose(const float* __restrict__ fused,
                                                   unsigned short* __restrict__ Vt) {
  __shared__ float tile[64][65];
  int st = blockIdx.x;
  int bk = blockIdx.y;
  const float* src = fused + ((size_t)(bk >> 3) * S_LEN + st * 64) * QKVN
                   + ((bk & 7) * 10 + 9) * HEADD;
  #pragma unroll
  for (int i = 0; i < 16; ++i) {
    int idx = i * 256 + threadIdx.x;
    int r = idx >> 6, d = idx & 63;
    tile[r][d] = src[(size_t)r * QKVN + d];
  }
  __syncthreads();
  unsigned short* dst = Vt + (size_t)bk * 64 * S_LEN + st * 64;
  #pragma unroll
  for (int i = 0; i < 16; ++i) {
    int idx = i * 256 + threadIdx.x;
    int d = idx >> 6, s = idx & 63;
    dst[(size_t)d * S_LEN + s] = f2bf(tile[s][d]);
  }
}

// ================================================================= GEMM 256²
// C[M][N] fp32 = A[M][K](bf16) * B[N][K](bf16)^T.
// 8-phase schedule (T3+T4): BM=BN=256, BK=64, 8 waves (2M x 4N), 512 threads,
// 128 KiB LDS (2-deep dbuf, each tile in 2 half-tiles of 128 rows x 64 k).
// Wave w: A row sub-blocks {ah*128 + (w>>2)*64}, B col sub-blocks
// {bh*128 + (w&3)*32} -> per phase all waves read exactly ONE half-tile region,
// so "stage 1 half-tile/phase + vmcnt(6) at phases 4/8" recycles regions with
// >=1 full barrier between last read and overwrite (race-free by construction).
// T2 swizzle: linear gload_lds dest + inverse-swizzled global source + swizzled
// ds_read (byte ^= (row&7)<<4). T5: setprio(1) around each 16-MFMA cluster.

#define LDSH   16384            // half-tile bytes (128 rows * 128B)
#define LDSB   32768            // per-buffer bytes (256 rows * 128B)

#define STAGE(gb, grow, lb, tkc) {                                             \
    const unsigned short* _s = (gb) + (size_t)((grow) + srow) * K              \
                             + ((tkc) << 5) * 2 + (skb >> 1);                  \
    gload16(_s,                 (lb) + (size_t)t * 16);                        \
    gload16(_s + (size_t)64 * K,(lb) + 8192 + (size_t)t * 16);                 \
  }

#define LDF(base, row, kb) (*(const bf16x8*)((base) + (size_t)(row) * 128 +    \
                            ((kb) ^ (((row) & 7) << 4))))

#define RD_A(ab, AH) {                                                         \
    _Pragma("unroll") for (int mi = 0; mi < 4; ++mi) {                         \
      int r = (AH) * 128 + wr + mi * 16 + l15;                                 \
      aF[mi][0] = LDF((ab), r, l4 * 16);                                       \
      aF[mi][1] = LDF((ab), r, 64 + l4 * 16);                                  \
    } }

#define RD_B(bb, BH, bf) {                                                     \
    _Pragma("unroll") for (int ni = 0; ni < 2; ++ni) {                         \
      int r = (BH) * 128 + wc + ni * 16 + l15;                                 \
      bf[ni][0] = LDF((bb), r, l4 * 16);                                       \
      bf[ni][1] = LDF((bb), r, 64 + l4 * 16);                                  \
    } }

#define MMA(AH, BH, bf) {                                                      \
    __builtin_amdgcn_s_setprio(1);                                             \
    _Pragma("unroll") for (int mi = 0; mi < 4; ++mi)                           \
    _Pragma("unroll") for (int ni = 0; ni < 2; ++ni) {                         \
      acc[AH][BH][mi][ni] = __builtin_amdgcn_mfma_f32_16x16x32_bf16(           \
          aF[mi][0], bf[ni][0], acc[AH][BH][mi][ni], 0, 0, 0);                 \
      acc[AH][BH][mi][ni] = __builtin_amdgcn_mfma_f32_16x16x32_bf16(           \
          aF[mi][1], bf[ni][1], acc[AH][BH][mi][ni], 0, 0, 0);                 \
    }                                                                          \
    __builtin_amdgcn_s_setprio(0); }

#define BAR() { __builtin_amdgcn_s_barrier(); asm volatile("" ::: "memory"); }
#define VMW(n) asm volatile("s_waitcnt vmcnt(" #n ")" ::: "memory")

__global__ __launch_bounds__(512, 2) void gemm256(const unsigned short* __restrict__ A,
                                                  const unsigned short* __restrict__ Bm,
                                                  float* __restrict__ C,
                                                  int M, int N, int K) {
  __shared__ char lds[131072];
  char* lA = lds;                 // [2 bufs][256 rows][128 B]
  char* lB = lds + 2 * LDSB;

  const int nkt = K >> 6;         // 64-wide K-tiles (even, >=2)
  const int ntx = N >> 8;
  // XCD-bijective swizzle (nwg % 8 == 0 at both call sites)
  const int nwg = gridDim.x;
  const int bid = blockIdx.x;
  const int wg  = (bid & 7) * (nwg >> 3) + (bid >> 3);
  const int m0  = (wg / ntx) << 8;
  const int n0  = (wg % ntx) << 8;

  const int t    = threadIdx.x;
  const int lane = t & 63;
  const int w    = t >> 6;
  const int wr   = (w >> 2) * 64;      // A row sub-block base within half
  const int wc   = (w & 3) * 32;       // B col sub-block base within half
  const int l15  = lane & 15, l4 = lane >> 4;

  // staging geometry: 1024 chunks of 16B per half-tile, 2 per thread
  const int srow = t >> 3;                              // row (i=0); i=1 adds 64
  const int skb  = ((t & 7) * 16) ^ ((srow & 7) << 4);  // same for both chunks

  f32x4 acc[2][2][4][2];
  #pragma unroll
  for (int a = 0; a < 2; ++a)
    #pragma unroll
    for (int b = 0; b < 2; ++b)
      #pragma unroll
      for (int mi = 0; mi < 4; ++mi)
        #pragma unroll
        for (int ni = 0; ni < 2; ++ni)
          acc[a][b][mi][ni] = (f32x4){0.f, 0.f, 0.f, 0.f};

  bf16x8 aF[4][2], bLo[2][2], bHi[2][2];

  // ---- prologue: tile0 (4 half-tiles) + tile1 (Alo,Blo,Ahi) ----
  STAGE(A,  m0,       lA,               0);
  STAGE(Bm, n0,       lB,               0);
  STAGE(A,  m0 + 128, lA + LDSH,        0);
  STAGE(Bm, n0 + 128, lB + LDSH,        0);
  STAGE(A,  m0,       lA + LDSB,        1);
  STAGE(Bm, n0,       lB + LDSB,        1);
  STAGE(A,  m0 + 128, lA + LDSB + LDSH, 1);
  VMW(6);
  BAR();

  for (int kt = 0; kt < nkt; kt += 2) {
    const int tk2 = (kt + 2 < nkt) ? kt + 2 : nkt - 1;
    const int tk3 = (kt + 3 < nkt) ? kt + 3 : nkt - 1;
    // ph1: quad(0,0) of tile kt (buf0); stage Bhi(kt+1)->buf1
    RD_A(lA, 0); RD_B(lB, 0, bLo);
    STAGE(Bm, n0 + 128, lB + LDSB + LDSH, kt + 1);
    BAR(); MMA(0, 0, bLo); BAR();
    // ph2: quad(0,1); stage Alo(kt+2)->buf0
    RD_B(lB, 1, bHi);
    STAGE(A, m0, lA, tk2);
    BAR(); MMA(0, 1, bHi); BAR();
    // ph3: quad(1,1); stage Blo(kt+2)->buf0
    RD_A(lA, 1);
    STAGE(Bm, n0, lB, tk2);
    BAR(); MMA(1, 1, bHi); BAR();
    // ph4: quad(1,0); stage Ahi(kt+2)->buf0; counted drain
    STAGE(A, m0 + 128, lA + LDSH, tk2);
    BAR(); MMA(1, 0, bLo); VMW(6); BAR();
    // ph5: quad(0,0) of tile kt+1 (buf1); stage Bhi(kt+2)->buf0
    RD_A(lA + LDSB, 0); RD_B(lB + LDSB, 0, bLo);
    STAGE(Bm, n0 + 128, lB + LDSH, tk2);
    BAR(); MMA(0, 0, bLo); BAR();
    // ph6: quad(0,1); stage Alo(kt+3)->buf1
    RD_B(lB + LDSB, 1, bHi);
    STAGE(A, m0, lA + LDSB, tk3);
    BAR(); MMA(0, 1, bHi); BAR();
    // ph7: quad(1,1); stage Blo(kt+3)->buf1
    RD_A(lA + LDSB, 1);
    STAGE(Bm, n0, lB + LDSB, tk3);
    BAR(); MMA(1, 1, bHi); BAR();
    // ph8: quad(1,0); stage Ahi(kt+3)->buf1; counted drain
    STAGE(A, m0 + 128, lA + LDSB + LDSH, tk3);
    BAR(); MMA(1, 0, bLo); VMW(6); BAR();
  }
  VMW(0);   // don't end with DMA-to-LDS in flight

  // epilogue: C/D layout col=lane&15, row=(lane>>4)*4+reg
  #pragma unroll
  for (int ah = 0; ah < 2; ++ah)
    #pragma unroll
    for (int bh = 0; bh < 2; ++bh)
      #pragma unroll
      for (int mi = 0; mi < 4; ++mi)
        #pragma unroll
        for (int ni = 0; ni < 2; ++ni) {
          int r0 = m0 + ah * 128 + wr + mi * 16 + l4 * 4;
          int c0 = n0 + bh * 128 + wc + ni * 16 + l15;
          #pragma unroll
          for (int r = 0; r < 4; ++r)
            C[(size_t)(r0 + r) * N + c0] = acc[ah][bh][mi][ni][r];
        }
}

// ---------------------------------------------------------------- attention
__global__ __launch_bounds__(256) void attn_fwd(const unsigned short* __restrict__ Qb,
                                                const unsigned short* __restrict__ Kb,
                                                const unsigned short* __restrict__ Vt,
                                                const float* __restrict__ alibi,
                                                unsigned short* __restrict__ ctx) {
  __shared__ unsigned short lQ[64 * 64];
  __shared__ unsigned short lK[64 * 64];
  __shared__ unsigned short lV[64 * 64];
  __shared__ unsigned short lP[64 * 64];

  const int qt  = blockIdx.x;
  const int bh  = blockIdx.y;
  const int b   = bh >> 6;
  const int h   = bh & 63;
  const int kvh = b * NKVH + (h >> 3);

  const int t    = threadIdx.x;
  const int lane = t & 63;
  const int w    = t >> 6;
  const int l15  = lane & 15, l4 = lane >> 4;

  const unsigned short* Qsrc = Qb + ((size_t)bh * S_LEN + qt * 64) * HEADD;
  const unsigned short* Ksrc = Kb + (size_t)kvh * S_LEN * HEADD;
  const unsigned short* Vsrc = Vt + (size_t)kvh * 64 * S_LEN;
  const float* al = alibi + (size_t)bh * S_LEN;

  #pragma unroll
  for (int i = 0; i < 2; ++i) {
    int c = i * 256 + t;
    int row = c >> 3;
    int kb  = ((c & 7) * 16) ^ ((row & 7) << 4);
    gload16(Qsrc + (size_t)row * HEADD + (kb >> 1), (char*)lQ + c * 16);
  }

  float mrun[4], lrun[4];
  f32x4 accO[4];
  #pragma unroll
  for (int r = 0; r < 4; ++r) { mrun[r] = -1e30f; lrun[r] = 0.f; }
  #pragma unroll
  for (int ni = 0; ni < 4; ++ni) accO[ni] = (f32x4){0.f, 0.f, 0.f, 0.f};

  for (int kt = 0; kt <= qt; ++kt) {
    #pragma unroll
    for (int i = 0; i < 2; ++i) {
      int c = i * 256 + t;
      int row = c >> 3;
      int kb  = ((c & 7) * 16) ^ ((row & 7) << 4);
      gload16(Ksrc + ((size_t)(kt * 64 + row)) * HEADD + (kb >> 1), (char*)lK + c * 16);
      gload16(Vsrc + (size_t)row * S_LEN + kt * 64 + (kb >> 1),     (char*)lV + c * 16);
    }
    __syncthreads();

    f32x4 accS[4];
    #pragma unroll
    for (int ni = 0; ni < 4; ++ni) accS[ni] = (f32x4){0.f, 0.f, 0.f, 0.f};
    const int qrow_l = w * 16 + l15;
    #pragma unroll
    for (int kk = 0; kk < 2; ++kk) {
      bf16x8 qF = *(const bf16x8*)((const char*)lQ + qrow_l * 128 +
                   ((kk * 64 + l4 * 16) ^ ((qrow_l & 7) << 4)));
      #pragma unroll
      for (int ni = 0; ni < 4; ++ni) {
        int krow = ni * 16 + l15;
        bf16x8 kF = *(const bf16x8*)((const char*)lK + krow * 128 +
                     ((kk * 64 + l4 * 16) ^ ((krow & 7) << 4)));
        accS[ni] = __builtin_amdgcn_mfma_f32_16x16x32_bf16(qF, kF, accS[ni], 0, 0, 0);
      }
    }

    const int q0 = qt * 64 + w * 16 + l4 * 4;
    float lv[4][4];
    float mt[4] = {-3e30f, -3e30f, -3e30f, -3e30f};
    #pragma unroll
    for (int ni = 0; ni < 4; ++ni) {
      int kc = kt * 64 + ni * 16 + l15;
      float ab = al[kc];
      #pragma unroll
      for (int r = 0; r < 4; ++r) {
        float x = (accS[ni][r] + ab) * INV_NORM;
        x = (kc > q0 + r) ? -1e9f : x;
        lv[ni][r] = x;
        mt[r] = fmaxf(mt[r], x);
      }
    }
    #pragma unroll
    for (int off = 1; off < 16; off <<= 1)
      #pragma unroll
      for (int r = 0; r < 4; ++r)
        mt[r] = fmaxf(mt[r], __shfl_xor(mt[r], off));

    float scale[4];
    #pragma unroll
    for (int r = 0; r < 4; ++r) {
      float mn = fmaxf(mrun[r], mt[r]);
      scale[r] = __expf(mrun[r] - mn);
      mrun[r]  = mn;
    }
    float ps[4] = {0.f, 0.f, 0.f, 0.f};
    const int prow0 = w * 16 + l4 * 4;
    #pragma unroll
    for (int ni = 0; ni < 4; ++ni) {
      #pragma unroll
      for (int r = 0; r < 4; ++r) {
        float pv = __expf(lv[ni][r] - mrun[r]);
        ps[r] += pv;
        int prow = prow0 + r;
        int pb   = ((ni * 16 + l15) * 2) ^ ((prow & 7) << 4);
        *(unsigned short*)((char*)lP + prow * 128 + pb) = f2bf(pv);
      }
    }
    #pragma unroll
    for (int off = 1; off < 16; off <<= 1)
      #pragma unroll
      for (int r = 0; r < 4; ++r)
        ps[r] += __shfl_xor(ps[r], off);
    #pragma unroll
    for (int r = 0; r < 4; ++r) lrun[r] = lrun[r] * scale[r] + ps[r];
    #pragma unroll
    for (int ni = 0; ni < 4; ++ni)
      #pragma unroll
      for (int r = 0; r < 4; ++r) accO[ni][r] *= scale[r];

    __syncthreads();

    #pragma unroll
    for (int kk = 0; kk < 2; ++kk) {
      bf16x8 pF = *(const bf16x8*)((const char*)lP + qrow_l * 128 +
                   ((kk * 64 + l4 * 16) ^ ((qrow_l & 7) << 4)));
      #pragma unroll
      for (int ni = 0; ni < 4; ++ni) {
        int vrow = ni * 16 + l15;
        bf16x8 vF = *(const bf16x8*)((const char*)lV + vrow * 128 +
                     ((kk * 64 + l4 * 16) ^ ((vrow & 7) << 4)));
        accO[ni] = __builtin_amdgcn_mfma_f32_16x16x32_bf16(pF, vF, accO[ni], 0, 0, 0);
      }
    }
    __syncthreads();
  }

  #pragma unroll
  for (int ni = 0; ni < 4; ++ni) {
    #pragma unroll
    for (int r = 0; r < 4; ++r) {
      int q = qt * 64 + w * 16 + l4 * 4 + r;
      float o = accO[ni][r] / lrun[r];
      ctx[((size_t)b * S_LEN + q) * (NHEADS * HEADD) + h * 64 + ni * 16 + l15] = f2bf(o);
    }
  }
}

// ---------------------------------------------------------------- launch
extern "C" void kernel_launch(void* const* d_in, const int* in_sizes, int n_in,
                              void* d_out, int out_size, void* d_ws, size_t ws_size,
                              hipStream_t stream) {
  const float* hidden = (const float*)d_in[0];
  const float* alibi  = (const float*)d_in[1];
  // d_in[2] = attention_mask: deterministically causal triu(k=1) -> analytic
  const float* Wqkv   = (const float*)d_in[3];
  const float* Wdense = (const float*)d_in[4];
  float* out = (float*)d_out;

  char* p = (char*)d_ws;
  auto alloc = [&](size_t bytes) {
    char* r = p; p += (bytes + 255) & ~(size_t)255; return r;
  };
  unsigned short* hiddenB = (unsigned short*)alloc((size_t)MTOK * HIDDIM * 2);
  unsigned short* WqkvB   = (unsigned short*)alloc((size_t)QKVN * HIDDIM * 2);
  unsigned short* WdenseB = (unsigned short*)alloc((size_t)HIDDIM * HIDDIM * 2);
  float*          fused   = (float*)alloc((size_t)MTOK * QKVN * 4);
  unsigned short* Qb      = (unsigned short*)alloc((size_t)2 * NHEADS * S_LEN * HEADD * 2);
  unsigned short* Kb      = (unsigned short*)alloc((size_t)2 * NKVH * S_LEN * HEADD * 2);
  unsigned short* Vt      = (unsigned short*)alloc((size_t)2 * NKVH * HEADD * S_LEN * 2);
  unsigned short* ctxB    = (unsigned short*)alloc((size_t)MTOK * HIDDIM * 2);
  float*          cosT    = (float*)alloc((size_t)S_LEN * 32 * 4);
  float*          sinT    = (float*)alloc((size_t)S_LEN * 32 * 4);

  cvt_bf16<<<1024, 256, 0, stream>>>(hidden, hiddenB, MTOK * HIDDIM / 4);
  cvt_bf16<<<2048, 256, 0, stream>>>(Wqkv,   WqkvB,   QKVN * HIDDIM / 4);
  cvt_bf16<<<2048, 256, 0, stream>>>(Wdense, WdenseB, HIDDIM * HIDDIM / 4);
  rope_table<<<(S_LEN * 32) / 256, 256, 0, stream>>>(cosT, sinT);

  gemm256<<<dim3((MTOK / 256) * (QKVN / 256)), 512, 0, stream>>>(
      hiddenB, WqkvB, fused, MTOK, QKVN, HIDDIM);

  rope_qk<<<(MTOK * NKVH * 9 * 32) / 256, 256, 0, stream>>>(fused, cosT, sinT, Qb, Kb);
  v_transpose<<<dim3(S_LEN / 64, 2 * NKVH), 256, 0, stream>>>(fused, Vt);

  attn_fwd<<<dim3(S_LEN / 64, 2 * NHEADS), 256, 0, stream>>>(Qb, Kb, Vt, alibi, ctxB);

  gemm256<<<dim3((MTOK / 256) * (HIDDIM / 256)), 512, 0, stream>>>(
      ctxB, WdenseB, out, MTOK, HIDDIM, HIDDIM);
}

// Round 3
// 517.315 us; speedup vs baseline: 1.1187x; 1.0383x over previous
//
#include <hip/hip_runtime.h>
#include <cstdint>
#include <cstddef>

// Problem constants (B=2, S=1024, HID=4096, NH=64, NKV=8, HD=64, G=8)
#define S_LEN   1024
#define HIDDIM  4096
#define NHEADS  64
#define NKVH    8
#define HEADD   64
#define QKVN    5120          // NKV*(G+2)*HD
#define MTOK    2048          // B*S
#define INV_NORM 0.125f       // 1/sqrt(64)

typedef __bf16  bf16x8 __attribute__((ext_vector_type(8)));
typedef float   f32x4  __attribute__((ext_vector_type(4)));
typedef float   f32x16 __attribute__((ext_vector_type(16)));

__device__ __forceinline__ unsigned short f2bf(float f) {
  union { float f; unsigned u; } x; x.f = f;
  unsigned r = x.u + 0x7fffu + ((x.u >> 16) & 1u);   // RNE
  return (unsigned short)(r >> 16);
}

// async global->LDS, 16B per lane. LDS dest must be wave-uniform base + lane*16.
__device__ __forceinline__ void gload16(const void* g, void* l) {
  __builtin_amdgcn_global_load_lds(
      (const __attribute__((address_space(1))) unsigned*)g,
      (__attribute__((address_space(3))) unsigned*)l, 16, 0, 0);
}

// ---------------------------------------------------------------- converts
__global__ __launch_bounds__(256) void cvt_bf16(const float* __restrict__ in,
                                                unsigned short* __restrict__ out,
                                                int n4) {
  int stride = gridDim.x * 256;
  for (int i = blockIdx.x * 256 + threadIdx.x; i < n4; i += stride) {
    float4 v = ((const float4*)in)[i];
    ushort4 o;
    o.x = f2bf(v.x); o.y = f2bf(v.y); o.z = f2bf(v.z); o.w = f2bf(v.w);
    ((ushort4*)out)[i] = o;
  }
}

// ---------------------------------------------------------------- RoPE table
__global__ __launch_bounds__(256) void rope_table(float* __restrict__ cosT,
                                                  float* __restrict__ sinT) {
  int i = blockIdx.x * 256 + threadIdx.x;   // S*32
  int s = i >> 5, d = i & 31;
  float inv_freq = powf(10000.f, -(float)d * (1.f / 32.f));
  float ang = (float)s * inv_freq;
  cosT[i] = cosf(ang);
  sinT[i] = sinf(ang);
}

// ---------------------------------------------------------------- alibi scale
__global__ __launch_bounds__(256) void alibi_scale(const float* __restrict__ in,
                                                   float* __restrict__ out, int n4) {
  int i = blockIdx.x * 256 + threadIdx.x;
  if (i < n4) {
    float4 v = ((const float4*)in)[i];
    v.x *= INV_NORM; v.y *= INV_NORM; v.z *= INV_NORM; v.w *= INV_NORM;
    ((float4*)out)[i] = v;
  }
}

// ------------------------------------------------- RoPE + GQA scatter (q,k)
// Q is pre-scaled by INV_NORM so attention logits = S + alibiS directly.
__global__ __launch_bounds__(256) void rope_qk(const float* __restrict__ fused,
                                               const float* __restrict__ cosT,
                                               const float* __restrict__ sinT,
                                               unsigned short* __restrict__ Qb,
                                               unsigned short* __restrict__ Kb) {
  int idx = blockIdx.x * 256 + threadIdx.x;  // ((bs*8+kv)*9+slot)*32+d
  int d    = idx & 31;
  int tmp  = idx >> 5;
  int slot = tmp % 9;  tmp /= 9;
  int kv   = tmp & 7;
  int bs   = tmp >> 3;
  int s    = bs & (S_LEN - 1);
  int b    = bs >> 10;

  const float* src = fused + (size_t)bs * QKVN + (kv * 10 + slot) * HEADD;
  float x0 = src[d], x1 = src[d + 32];
  float c  = cosT[s * 32 + d];
  float sn = sinT[s * 32 + d];
  float o0 = x0 * c - x1 * sn;
  float o1 = x1 * c + x0 * sn;

  if (slot < 8) {
    int h = kv * 8 + slot;
    size_t base = (((size_t)(b * NHEADS + h)) * S_LEN + s) * HEADD;
    Qb[base + d]      = f2bf(o0 * INV_NORM);
    Qb[base + d + 32] = f2bf(o1 * INV_NORM);
  } else {
    size_t base = (((size_t)(b * NKVH + kv)) * S_LEN + s) * HEADD;
    Kb[base + d]      = f2bf(o0);
    Kb[base + d + 32] = f2bf(o1);
  }
}

// --------------------------------------------------------- V transpose
__global__ __launch_bounds__(256) void v_transpose(const float* __restrict__ fused,
                                                   unsigned short* __restrict__ Vt) {
  __shared__ float tile[64][65];
  int st = blockIdx.x;
  int bk = blockIdx.y;
  const float* src = fused + ((size_t)(bk >> 3) * S_LEN + st * 64) * QKVN
                   + ((bk & 7) * 10 + 9) * HEADD;
  #pragma unroll
  for (int i = 0; i < 16; ++i) {
    int idx = i * 256 + threadIdx.x;
    int r = idx >> 6, d = idx & 63;
    tile[r][d] = src[(size_t)r * QKVN + d];
  }
  __syncthreads();
  unsigned short* dst = Vt + (size_t)bk * 64 * S_LEN + st * 64;
  #pragma unroll
  for (int i = 0; i < 16; ++i) {
    int idx = i * 256 + threadIdx.x;
    int d = idx >> 6, s = idx & 63;
    dst[(size_t)d * S_LEN + s] = f2bf(tile[s][d]);
  }
}

// ================================================================= GEMM 256²
// (unchanged from round 1 — 8-phase T3+T4+T5, T2 swizzle, XCD-bijective)
#define LDSH   16384
#define LDSB   32768

#define STAGE(gb, grow, lb, tkc) {                                             \
    const unsigned short* _s = (gb) + (size_t)((grow) + srow) * K              \
                             + ((tkc) << 5) * 2 + (skb >> 1);                  \
    gload16(_s,                 (lb) + (size_t)t * 16);                        \
    gload16(_s + (size_t)64 * K,(lb) + 8192 + (size_t)t * 16);                 \
  }

#define LDF(base, row, kb) (*(const bf16x8*)((base) + (size_t)(row) * 128 +    \
                            ((kb) ^ (((row) & 7) << 4))))

#define RD_A(ab, AH) {                                                         \
    _Pragma("unroll") for (int mi = 0; mi < 4; ++mi) {                         \
      int r = (AH) * 128 + wr + mi * 16 + l15;                                 \
      aF[mi][0] = LDF((ab), r, l4 * 16);                                       \
      aF[mi][1] = LDF((ab), r, 64 + l4 * 16);                                  \
    } }

#define RD_B(bb, BH, bf) {                                                     \
    _Pragma("unroll") for (int ni = 0; ni < 2; ++ni) {                         \
      int r = (BH) * 128 + wc + ni * 16 + l15;                                 \
      bf[ni][0] = LDF((bb), r, l4 * 16);                                       \
      bf[ni][1] = LDF((bb), r, 64 + l4 * 16);                                  \
    } }

#define MMA(AH, BH, bf) {                                                      \
    __builtin_amdgcn_s_setprio(1);                                             \
    _Pragma("unroll") for (int mi = 0; mi < 4; ++mi)                           \
    _Pragma("unroll") for (int ni = 0; ni < 2; ++ni) {                         \
      acc[AH][BH][mi][ni] = __builtin_amdgcn_mfma_f32_16x16x32_bf16(           \
          aF[mi][0], bf[ni][0], acc[AH][BH][mi][ni], 0, 0, 0);                 \
      acc[AH][BH][mi][ni] = __builtin_amdgcn_mfma_f32_16x16x32_bf16(           \
          aF[mi][1], bf[ni][1], acc[AH][BH][mi][ni], 0, 0, 0);                 \
    }                                                                          \
    __builtin_amdgcn_s_setprio(0); }

#define BAR() { __builtin_amdgcn_s_barrier(); asm volatile("" ::: "memory"); }
#define VMW(n) asm volatile("s_waitcnt vmcnt(" #n ")" ::: "memory")

__global__ __launch_bounds__(512, 2) void gemm256(const unsigned short* __restrict__ A,
                                                  const unsigned short* __restrict__ Bm,
                                                  float* __restrict__ C,
                                                  int M, int N, int K) {
  __shared__ char lds[131072];
  char* lA = lds;
  char* lB = lds + 2 * LDSB;

  const int nkt = K >> 6;
  const int ntx = N >> 8;
  const int nwg = gridDim.x;
  const int bid = blockIdx.x;
  const int wg  = (bid & 7) * (nwg >> 3) + (bid >> 3);
  const int m0  = (wg / ntx) << 8;
  const int n0  = (wg % ntx) << 8;

  const int t    = threadIdx.x;
  const int lane = t & 63;
  const int w    = t >> 6;
  const int wr   = (w >> 2) * 64;
  const int wc   = (w & 3) * 32;
  const int l15  = lane & 15, l4 = lane >> 4;

  const int srow = t >> 3;
  const int skb  = ((t & 7) * 16) ^ ((srow & 7) << 4);

  f32x4 acc[2][2][4][2];
  #pragma unroll
  for (int a = 0; a < 2; ++a)
    #pragma unroll
    for (int b = 0; b < 2; ++b)
      #pragma unroll
      for (int mi = 0; mi < 4; ++mi)
        #pragma unroll
        for (int ni = 0; ni < 2; ++ni)
          acc[a][b][mi][ni] = (f32x4){0.f, 0.f, 0.f, 0.f};

  bf16x8 aF[4][2], bLo[2][2], bHi[2][2];

  STAGE(A,  m0,       lA,               0);
  STAGE(Bm, n0,       lB,               0);
  STAGE(A,  m0 + 128, lA + LDSH,        0);
  STAGE(Bm, n0 + 128, lB + LDSH,        0);
  STAGE(A,  m0,       lA + LDSB,        1);
  STAGE(Bm, n0,       lB + LDSB,        1);
  STAGE(A,  m0 + 128, lA + LDSB + LDSH, 1);
  VMW(6);
  BAR();

  for (int kt = 0; kt < nkt; kt += 2) {
    const int tk2 = (kt + 2 < nkt) ? kt + 2 : nkt - 1;
    const int tk3 = (kt + 3 < nkt) ? kt + 3 : nkt - 1;
    RD_A(lA, 0); RD_B(lB, 0, bLo);
    STAGE(Bm, n0 + 128, lB + LDSB + LDSH, kt + 1);
    BAR(); MMA(0, 0, bLo); BAR();
    RD_B(lB, 1, bHi);
    STAGE(A, m0, lA, tk2);
    BAR(); MMA(0, 1, bHi); BAR();
    RD_A(lA, 1);
    STAGE(Bm, n0, lB, tk2);
    BAR(); MMA(1, 1, bHi); BAR();
    STAGE(A, m0 + 128, lA + LDSH, tk2);
    BAR(); MMA(1, 0, bLo); VMW(6); BAR();
    RD_A(lA + LDSB, 0); RD_B(lB + LDSB, 0, bLo);
    STAGE(Bm, n0 + 128, lB + LDSH, tk2);
    BAR(); MMA(0, 0, bLo); BAR();
    RD_B(lB + LDSB, 1, bHi);
    STAGE(A, m0, lA + LDSB, tk3);
    BAR(); MMA(0, 1, bHi); BAR();
    RD_A(lA + LDSB, 1);
    STAGE(Bm, n0, lB + LDSB, tk3);
    BAR(); MMA(1, 1, bHi); BAR();
    STAGE(A, m0 + 128, lA + LDSB + LDSH, tk3);
    BAR(); MMA(1, 0, bLo); VMW(6); BAR();
  }
  VMW(0);

  #pragma unroll
  for (int ah = 0; ah < 2; ++ah)
    #pragma unroll
    for (int bh = 0; bh < 2; ++bh)
      #pragma unroll
      for (int mi = 0; mi < 4; ++mi)
        #pragma unroll
        for (int ni = 0; ni < 2; ++ni) {
          int r0 = m0 + ah * 128 + wr + mi * 16 + l4 * 4;
          int c0 = n0 + bh * 128 + wc + ni * 16 + l15;
          #pragma unroll
          for (int r = 0; r < 4; ++r)
            C[(size_t)(r0 + r) * N + c0] = acc[ah][bh][mi][ni][r];
        }
}

// ================================================================ attention
// 32x32 swapped-operand flash attention. Block = 128 q rows (4 waves x 32 q),
// KVBLK=64, double-buffered K/V LDS (counted vmcnt(4), raw s_barrier, 2/iter).
// S^T = mfma(K,Q): lane holds full 64-kv P row for q=lane&31 (half in partner
// lane hi^1). Softmax in-register: 1 shfl_xor(32) per reduce. P repacked to
// PV B-frags via cvt + 8 shfl_xor(32) + selects (no LDS round-trip).
__global__ __launch_bounds__(256, 2) void attn_fwd(
    const unsigned short* __restrict__ Qb,   // [B*NH, S, 64] bf16 (x INV_NORM)
    const unsigned short* __restrict__ Kb,   // [B*NKV, S, 64] bf16
    const unsigned short* __restrict__ Vt,   // [B*NKV, 64, S] bf16
    const float* __restrict__ alibiS,        // [B*NH, S] f32 (x INV_NORM)
    unsigned short* __restrict__ ctx) {
  __shared__ char lds[32768];                // [2 buf][ K 8KB | V 8KB ]

  const int qt  = 7 - blockIdx.x;            // longest-first dispatch
  const int bh  = blockIdx.y;
  const int b   = bh >> 6, h = bh & 63;
  const int kvh = b * NKVH + (h >> 3);
  const int qbase = qt * 128;
  const int nkt = 2 * qt + 2;

  const int t    = threadIdx.x;
  const int lane = t & 63;
  const int w    = t >> 6;
  const int l31  = lane & 31;
  const int hi   = lane >> 5;

  const unsigned short* Ksrc = Kb + (size_t)kvh * (S_LEN * HEADD);
  const unsigned short* Vsrc = Vt + (size_t)kvh * (HEADD * S_LEN);
  const float* al = alibiS + (size_t)bh * S_LEN;

  // stage one 64x64 bf16 tile pair (K rows=kv, V rows=d): 2 chunks/thread each
  #define ASTG(buf, kt_) {                                                     \
    _Pragma("unroll") for (int i = 0; i < 2; ++i) {                            \
      int c = i * 256 + t; int row = c >> 3;                                   \
      int kb = ((c & 7) * 16) ^ ((row & 7) << 4);                              \
      gload16(Ksrc + ((size_t)((kt_) * 64 + row)) * HEADD + (kb >> 1),         \
              lds + (buf) * 16384 + c * 16);                                   \
      gload16(Vsrc + (size_t)row * S_LEN + (kt_) * 64 + (kb >> 1),             \
              lds + (buf) * 16384 + 8192 + c * 16);                            \
    } }

  // hoist Q fragments: q = qbase + w*32 + l31, frag ks: d = ks*16 + hi*8 + j
  const int qrow = qbase + w * 32 + l31;
  const unsigned short* Qr = Qb + ((size_t)bh * S_LEN + qrow) * HEADD;
  bf16x8 qF[4];
  #pragma unroll
  for (int ks = 0; ks < 4; ++ks)
    qF[ks] = *(const bf16x8*)(Qr + ks * 16 + hi * 8);

  f32x16 accO[2];
  #pragma unroll
  for (int di = 0; di < 2; ++di)
    #pragma unroll
    for (int r = 0; r < 16; ++r) accO[di][r] = 0.f;
  float mrun = -1e30f, lrun = 0.f;

  ASTG(0, 0);
  for (int kt = 0; kt < nkt; ++kt) {
    const int ktn = (kt + 1 < nkt) ? kt + 1 : kt;   // clamped re-stage
    ASTG((kt + 1) & 1, ktn);
    VMW(4);                                          // current buf complete
    BAR();
    const char* lK = lds + (kt & 1) * 16384;
    const char* lV = lK + 8192;

    // alibi for this tile: kv_local = blk*32 + 8g + 4hi + {0..3}
    float4 a4[2][4];
    #pragma unroll
    for (int blk = 0; blk < 2; ++blk)
      #pragma unroll
      for (int g = 0; g < 4; ++g)
        a4[blk][g] = *(const float4*)(al + kt * 64 + blk * 32 + 8 * g + 4 * hi);

    // ---- S^T = K Q^T : accS[blk] covers kv = blk*32.., q = l31
    f32x16 accS[2];
    #pragma unroll
    for (int blk = 0; blk < 2; ++blk)
      #pragma unroll
      for (int r = 0; r < 16; ++r) accS[blk][r] = 0.f;
    #pragma unroll
    for (int ks = 0; ks < 4; ++ks)
      #pragma unroll
      for (int blk = 0; blk < 2; ++blk) {
        int row = blk * 32 + l31;
        bf16x8 kF = *(const bf16x8*)(lK + row * 128 +
                     ((ks * 32 + hi * 16) ^ ((row & 7) << 4)));
        accS[blk] = __builtin_amdgcn_mfma_f32_32x32x16_bf16(kF, qF[ks], accS[blk], 0, 0, 0);
      }

    // ---- online softmax (lane-local row; partner lane holds other 32 kv)
    const bool domask = (kt >= 2 * qt);
    float mt = -1e30f;
    #pragma unroll
    for (int blk = 0; blk < 2; ++blk)
      #pragma unroll
      for (int r = 0; r < 16; ++r) {
        float x = accS[blk][r] + (&a4[blk][r >> 2].x)[r & 3];
        if (domask) {
          int kv = kt * 64 + blk * 32 + 8 * (r >> 2) + 4 * hi + (r & 3);
          x = (kv > qrow) ? -1e30f : x;
        }
        accS[blk][r] = x;
        mt = fmaxf(mt, x);
      }
    mt = fmaxf(mt, __shfl_xor(mt, 32));
    if (!__all(mt - mrun <= 8.0f)) {       // T13 defer-max
      float mn = fmaxf(mrun, mt);
      float sc = __expf(mrun - mn);
      lrun *= sc;
      #pragma unroll
      for (int di = 0; di < 2; ++di)
        #pragma unroll
        for (int r = 0; r < 16; ++r) accO[di][r] *= sc;
      mrun = mn;
    }
    float s_own = 0.f;
    #pragma unroll
    for (int blk = 0; blk < 2; ++blk)
      #pragma unroll
      for (int r = 0; r < 16; ++r) {
        float p = __expf(accS[blk][r] - mrun);
        accS[blk][r] = p;
        s_own += p;
      }
    lrun += s_own + __shfl_xor(s_own, 32);

    // ---- pack P to bf16 pairs: W[blk][g][h] = (p[4g+2h], p[4g+2h+1])
    unsigned W[2][4][2];
    #pragma unroll
    for (int blk = 0; blk < 2; ++blk)
      #pragma unroll
      for (int g = 0; g < 4; ++g)
        #pragma unroll
        for (int hh = 0; hh < 2; ++hh) {
          unsigned lo = (unsigned)__builtin_bit_cast(unsigned short,
                          (__bf16)accS[blk][g * 4 + 2 * hh]);
          unsigned hi16 = (unsigned)__builtin_bit_cast(unsigned short,
                          (__bf16)accS[blk][g * 4 + 2 * hh + 1]);
          W[blk][g][hh] = lo | (hi16 << 16);
        }

    // ---- exchange to PV B-frags uB[q16]: [q=l31][k_kv = q16*16 + hi*8 + j]
    bf16x8 uB[4];
    #pragma unroll
    for (int q16 = 0; q16 < 4; ++q16) {
      const int blk = q16 >> 1, g0 = 2 * (q16 & 1);
      unsigned A0 = W[blk][g0][0],     A1 = W[blk][g0][1];
      unsigned B0 = W[blk][g0 + 1][0], B1 = W[blk][g0 + 1][1];
      unsigned own0 = hi ? B0 : A0, own1 = hi ? B1 : A1;
      unsigned sw0  = hi ? A0 : B0, sw1  = hi ? A1 : B1;
      unsigned X0 = (unsigned)__shfl_xor((int)sw0, 32);
      unsigned X1 = (unsigned)__shfl_xor((int)sw1, 32);
      union { unsigned u[4]; bf16x8 v; } U;
      U.u[0] = hi ? X0 : own0;
      U.u[1] = hi ? X1 : own1;
      U.u[2] = hi ? own0 : X0;
      U.u[3] = hi ? own1 : X1;
      uB[q16] = U.v;
    }

    // ---- O^T += V^T P^T : accO[di] covers d = di*32.., q = l31
    #pragma unroll
    for (int q16 = 0; q16 < 4; ++q16)
      #pragma unroll
      for (int di = 0; di < 2; ++di) {
        int row = di * 32 + l31;
        bf16x8 vF = *(const bf16x8*)(lV + row * 128 +
                     ((q16 * 32 + hi * 16) ^ ((row & 7) << 4)));
        accO[di] = __builtin_amdgcn_mfma_f32_32x32x16_bf16(vF, uB[q16], accO[di], 0, 0, 0);
      }
    BAR();   // all reads of this buf done before it is restaged
  }
  VMW(0);    // drain clamped re-stage DMA before exit

  // ---- epilogue: ctx[b, q, h*64 + d], d = di*32 + 8g + 4hi + r
  float inv_l = 1.0f / lrun;
  #pragma unroll
  for (int di = 0; di < 2; ++di)
    #pragma unroll
    for (int g = 0; g < 4; ++g) {
      ushort4 o;
      o.x = __builtin_bit_cast(unsigned short, (__bf16)(accO[di][g * 4 + 0] * inv_l));
      o.y = __builtin_bit_cast(unsigned short, (__bf16)(accO[di][g * 4 + 1] * inv_l));
      o.z = __builtin_bit_cast(unsigned short, (__bf16)(accO[di][g * 4 + 2] * inv_l));
      o.w = __builtin_bit_cast(unsigned short, (__bf16)(accO[di][g * 4 + 3] * inv_l));
      int d = di * 32 + 8 * g + 4 * hi;
      *(ushort4*)(ctx + ((size_t)b * S_LEN + qrow) * (NHEADS * HEADD) + h * 64 + d) = o;
    }
  #undef ASTG
}

// ---------------------------------------------------------------- launch
extern "C" void kernel_launch(void* const* d_in, const int* in_sizes, int n_in,
                              void* d_out, int out_size, void* d_ws, size_t ws_size,
                              hipStream_t stream) {
  const float* hidden = (const float*)d_in[0];
  const float* alibi  = (const float*)d_in[1];
  // d_in[2] = attention_mask: deterministically causal triu(k=1) -> analytic
  const float* Wqkv   = (const float*)d_in[3];
  const float* Wdense = (const float*)d_in[4];
  float* out = (float*)d_out;

  char* p = (char*)d_ws;
  auto alloc = [&](size_t bytes) {
    char* r = p; p += (bytes + 255) & ~(size_t)255; return r;
  };
  unsigned short* hiddenB = (unsigned short*)alloc((size_t)MTOK * HIDDIM * 2);
  unsigned short* WqkvB   = (unsigned short*)alloc((size_t)QKVN * HIDDIM * 2);
  unsigned short* WdenseB = (unsigned short*)alloc((size_t)HIDDIM * HIDDIM * 2);
  float*          fused   = (float*)alloc((size_t)MTOK * QKVN * 4);
  unsigned short* Qb      = (unsigned short*)alloc((size_t)2 * NHEADS * S_LEN * HEADD * 2);
  unsigned short* Kb      = (unsigned short*)alloc((size_t)2 * NKVH * S_LEN * HEADD * 2);
  unsigned short* Vt      = (unsigned short*)alloc((size_t)2 * NKVH * HEADD * S_LEN * 2);
  unsigned short* ctxB    = (unsigned short*)alloc((size_t)MTOK * HIDDIM * 2);
  float*          cosT    = (float*)alloc((size_t)S_LEN * 32 * 4);
  float*          sinT    = (float*)alloc((size_t)S_LEN * 32 * 4);
  float*          alibiS  = (float*)alloc((size_t)2 * NHEADS * S_LEN * 4);

  cvt_bf16<<<1024, 256, 0, stream>>>(hidden, hiddenB, MTOK * HIDDIM / 4);
  cvt_bf16<<<2048, 256, 0, stream>>>(Wqkv,   WqkvB,   QKVN * HIDDIM / 4);
  cvt_bf16<<<2048, 256, 0, stream>>>(Wdense, WdenseB, HIDDIM * HIDDIM / 4);
  rope_table<<<(S_LEN * 32) / 256, 256, 0, stream>>>(cosT, sinT);
  alibi_scale<<<(2 * NHEADS * S_LEN / 4 + 255) / 256, 256, 0, stream>>>(
      alibi, alibiS, 2 * NHEADS * S_LEN / 4);

  gemm256<<<dim3((MTOK / 256) * (QKVN / 256)), 512, 0, stream>>>(
      hiddenB, WqkvB, fused, MTOK, QKVN, HIDDIM);

  rope_qk<<<(MTOK * NKVH * 9 * 32) / 256, 256, 0, stream>>>(fused, cosT, sinT, Qb, Kb);
  v_transpose<<<dim3(S_LEN / 64, 2 * NKVH), 256, 0, stream>>>(fused, Vt);

  attn_fwd<<<dim3(S_LEN / 128, 2 * NHEADS), 256, 0, stream>>>(Qb, Kb, Vt, alibiS, ctxB);

  gemm256<<<dim3((MTOK / 256) * (HIDDIM / 256)), 512, 0, stream>>>(
      ctxB, WdenseB, out, MTOK, HIDDIM, HIDDIM);
}

// Round 4
// 476.576 us; speedup vs baseline: 1.2144x; 1.0855x over previous
//
#include <hip/hip_runtime.h>
#include <cstdint>
#include <cstddef>

// Problem constants (B=2, S=1024, HID=4096, NH=64, NKV=8, HD=64, G=8)
#define S_LEN   1024
#define HIDDIM  4096
#define NHEADS  64
#define NKVH    8
#define HEADD   64
#define QKVN    5120          // NKV*(G+2)*HD
#define MTOK    2048          // B*S
#define INV_NORM 0.125f       // 1/sqrt(64)

typedef __bf16  bf16x8 __attribute__((ext_vector_type(8)));
typedef float   f32x4  __attribute__((ext_vector_type(4)));
typedef float   f32x16 __attribute__((ext_vector_type(16)));

__device__ __forceinline__ unsigned short f2bf(float f) {
  union { float f; unsigned u; } x; x.f = f;
  unsigned r = x.u + 0x7fffu + ((x.u >> 16) & 1u);   // RNE
  return (unsigned short)(r >> 16);
}

// async global->LDS, 16B per lane. LDS dest must be wave-uniform base + lane*16.
__device__ __forceinline__ void gload16(const void* g, void* l) {
  __builtin_amdgcn_global_load_lds(
      (const __attribute__((address_space(1))) unsigned*)g,
      (__attribute__((address_space(3))) unsigned*)l, 16, 0, 0);
}

// ---------------------------------------------------------------- converts
__global__ __launch_bounds__(256) void cvt_bf16(const float* __restrict__ in,
                                                unsigned short* __restrict__ out,
                                                int n4) {
  int stride = gridDim.x * 256;
  for (int i = blockIdx.x * 256 + threadIdx.x; i < n4; i += stride) {
    float4 v = ((const float4*)in)[i];
    ushort4 o;
    o.x = f2bf(v.x); o.y = f2bf(v.y); o.z = f2bf(v.z); o.w = f2bf(v.w);
    ((ushort4*)out)[i] = o;
  }
}

// ------------------------------------------------- RoPE + GQA scatter (q,k)
// Q is pre-scaled by INV_NORM so attention logits = S + alibiS directly.
__global__ __launch_bounds__(256) void rope_qk(const float* __restrict__ fused,
                                               const float* __restrict__ cosT,
                                               const float* __restrict__ sinT,
                                               unsigned short* __restrict__ Qb,
                                               unsigned short* __restrict__ Kb) {
  int idx = blockIdx.x * 256 + threadIdx.x;  // ((bs*8+kv)*9+slot)*32+d
  int d    = idx & 31;
  int tmp  = idx >> 5;
  int slot = tmp % 9;  tmp /= 9;
  int kv   = tmp & 7;
  int bs   = tmp >> 3;
  int s    = bs & (S_LEN - 1);
  int b    = bs >> 10;

  const float* src = fused + (size_t)bs * QKVN + (kv * 10 + slot) * HEADD;
  float x0 = src[d], x1 = src[d + 32];
  float c  = cosT[s * 32 + d];
  float sn = sinT[s * 32 + d];
  float o0 = x0 * c - x1 * sn;
  float o1 = x1 * c + x0 * sn;

  if (slot < 8) {
    int h = kv * 8 + slot;
    size_t base = (((size_t)(b * NHEADS + h)) * S_LEN + s) * HEADD;
    Qb[base + d]      = f2bf(o0 * INV_NORM);
    Qb[base + d + 32] = f2bf(o1 * INV_NORM);
  } else {
    size_t base = (((size_t)(b * NKVH + kv)) * S_LEN + s) * HEADD;
    Kb[base + d]      = f2bf(o0);
    Kb[base + d + 32] = f2bf(o1);
  }
}

// --------------------------------------------------------- V transpose
__global__ __launch_bounds__(256) void v_transpose(const float* __restrict__ fused,
                                                   unsigned short* __restrict__ Vt) {
  __shared__ float tile[64][65];
  int st = blockIdx.x;
  int bk = blockIdx.y;
  const float* src = fused + ((size_t)(bk >> 3) * S_LEN + st * 64) * QKVN
                   + ((bk & 7) * 10 + 9) * HEADD;
  #pragma unroll
  for (int i = 0; i < 16; ++i) {
    int idx = i * 256 + threadIdx.x;
    int r = idx >> 6, d = idx & 63;
    tile[r][d] = src[(size_t)r * QKVN + d];
  }
  __syncthreads();
  unsigned short* dst = Vt + (size_t)bk * 64 * S_LEN + st * 64;
  #pragma unroll
  for (int i = 0; i < 16; ++i) {
    int idx = i * 256 + threadIdx.x;
    int d = idx >> 6, s = idx & 63;
    dst[(size_t)d * S_LEN + s] = f2bf(tile[s][d]);
  }
}

// ---------------------------------------------------------------- reduce add
__global__ __launch_bounds__(256) void reduce_add(const float* __restrict__ a,
                                                  const float* __restrict__ b,
                                                  float* __restrict__ o, int n4) {
  int i = blockIdx.x * 256 + threadIdx.x;
  if (i < n4) {
    float4 x = ((const float4*)a)[i];
    float4 y = ((const float4*)b)[i];
    x.x += y.x; x.y += y.y; x.z += y.z; x.w += y.w;
    ((float4*)o)[i] = x;
  }
}

// ================================================================= GEMM 256²
// 8-phase T3+T4+T5 core (verified round 1), generalized with lda/ldb/kbase/
// nkt/ldc for split-K and non-square use. C[M][N] fp32 += over K-range of
// A[.][lda](bf16) * B[.][ldb](bf16)^T at tile (m0,n0).
#define LDSH   16384
#define LDSB   32768

#define STAGE(gb, grow, lb, tkc, ld) {                                         \
    const unsigned short* _s = (gb) + (size_t)((grow) + srow) * (ld)           \
                             + kbase + ((tkc) << 6) + (skb >> 1);              \
    gload16(_s,                  (lb) + (size_t)t * 16);                       \
    gload16(_s + (size_t)64 * (ld), (lb) + 8192 + (size_t)t * 16);             \
  }

#define LDF(base, row, kb) (*(const bf16x8*)((base) + (size_t)(row) * 128 +    \
                            ((kb) ^ (((row) & 7) << 4))))

#define RD_A(ab, AH) {                                                         \
    _Pragma("unroll") for (int mi = 0; mi < 4; ++mi) {                         \
      int r = (AH) * 128 + wr + mi * 16 + l15;                                 \
      aF[mi][0] = LDF((ab), r, l4 * 16);                                       \
      aF[mi][1] = LDF((ab), r, 64 + l4 * 16);                                  \
    } }

#define RD_B(bb, BH, bf) {                                                     \
    _Pragma("unroll") for (int ni = 0; ni < 2; ++ni) {                         \
      int r = (BH) * 128 + wc + ni * 16 + l15;                                 \
      bf[ni][0] = LDF((bb), r, l4 * 16);                                       \
      bf[ni][1] = LDF((bb), r, 64 + l4 * 16);                                  \
    } }

#define MMA(AH, BH, bf) {                                                      \
    __builtin_amdgcn_s_setprio(1);                                             \
    _Pragma("unroll") for (int mi = 0; mi < 4; ++mi)                           \
    _Pragma("unroll") for (int ni = 0; ni < 2; ++ni) {                         \
      acc[AH][BH][mi][ni] = __builtin_amdgcn_mfma_f32_16x16x32_bf16(           \
          aF[mi][0], bf[ni][0], acc[AH][BH][mi][ni], 0, 0, 0);                 \
      acc[AH][BH][mi][ni] = __builtin_amdgcn_mfma_f32_16x16x32_bf16(           \
          aF[mi][1], bf[ni][1], acc[AH][BH][mi][ni], 0, 0, 0);                 \
    }                                                                          \
    __builtin_amdgcn_s_setprio(0); }

#define BAR() { __builtin_amdgcn_s_barrier(); asm volatile("" ::: "memory"); }
#define VMW(n) asm volatile("s_waitcnt vmcnt(" #n ")" ::: "memory")

__device__ __forceinline__ void gemm256_core(
    const unsigned short* __restrict__ A, int lda,
    const unsigned short* __restrict__ Bm, int ldb,
    float* __restrict__ C, int ldc,
    int m0, int n0, int kbase, int nkt) {
  __shared__ char lds[131072];
  char* lA = lds;
  char* lB = lds + 2 * LDSB;

  const int t    = threadIdx.x;
  const int lane = t & 63;
  const int w    = t >> 6;
  const int wr   = (w >> 2) * 64;
  const int wc   = (w & 3) * 32;
  const int l15  = lane & 15, l4 = lane >> 4;

  const int srow = t >> 3;
  const int skb  = ((t & 7) * 16) ^ ((srow & 7) << 4);

  f32x4 acc[2][2][4][2];
  #pragma unroll
  for (int a = 0; a < 2; ++a)
    #pragma unroll
    for (int b = 0; b < 2; ++b)
      #pragma unroll
      for (int mi = 0; mi < 4; ++mi)
        #pragma unroll
        for (int ni = 0; ni < 2; ++ni)
          acc[a][b][mi][ni] = (f32x4){0.f, 0.f, 0.f, 0.f};

  bf16x8 aF[4][2], bLo[2][2], bHi[2][2];

  STAGE(A,  m0,       lA,               0, lda);
  STAGE(Bm, n0,       lB,               0, ldb);
  STAGE(A,  m0 + 128, lA + LDSH,        0, lda);
  STAGE(Bm, n0 + 128, lB + LDSH,        0, ldb);
  STAGE(A,  m0,       lA + LDSB,        1, lda);
  STAGE(Bm, n0,       lB + LDSB,        1, ldb);
  STAGE(A,  m0 + 128, lA + LDSB + LDSH, 1, lda);
  VMW(6);
  BAR();

  for (int kt = 0; kt < nkt; kt += 2) {
    const int tk2 = (kt + 2 < nkt) ? kt + 2 : nkt - 1;
    const int tk3 = (kt + 3 < nkt) ? kt + 3 : nkt - 1;
    RD_A(lA, 0); RD_B(lB, 0, bLo);
    STAGE(Bm, n0 + 128, lB + LDSB + LDSH, kt + 1, ldb);
    BAR(); MMA(0, 0, bLo); BAR();
    RD_B(lB, 1, bHi);
    STAGE(A, m0, lA, tk2, lda);
    BAR(); MMA(0, 1, bHi); BAR();
    RD_A(lA, 1);
    STAGE(Bm, n0, lB, tk2, ldb);
    BAR(); MMA(1, 1, bHi); BAR();
    STAGE(A, m0 + 128, lA + LDSH, tk2, lda);
    BAR(); MMA(1, 0, bLo); VMW(6); BAR();
    RD_A(lA + LDSB, 0); RD_B(lB + LDSB, 0, bLo);
    STAGE(Bm, n0 + 128, lB + LDSH, tk2, ldb);
    BAR(); MMA(0, 0, bLo); BAR();
    RD_B(lB + LDSB, 1, bHi);
    STAGE(A, m0, lA + LDSB, tk3, lda);
    BAR(); MMA(0, 1, bHi); BAR();
    RD_A(lA + LDSB, 1);
    STAGE(Bm, n0, lB + LDSB, tk3, ldb);
    BAR(); MMA(1, 1, bHi); BAR();
    STAGE(A, m0 + 128, lA + LDSB + LDSH, tk3, lda);
    BAR(); MMA(1, 0, bLo); VMW(6); BAR();
  }
  VMW(0);

  #pragma unroll
  for (int ah = 0; ah < 2; ++ah)
    #pragma unroll
    for (int bh = 0; bh < 2; ++bh)
      #pragma unroll
      for (int mi = 0; mi < 4; ++mi)
        #pragma unroll
        for (int ni = 0; ni < 2; ++ni) {
          int r0 = m0 + ah * 128 + wr + mi * 16 + l4 * 4;
          int c0 = n0 + bh * 128 + wc + ni * 16 + l15;
          #pragma unroll
          for (int r = 0; r < 4; ++r)
            C[(size_t)(r0 + r) * ldc + c0] = acc[ah][bh][mi][ni][r];
        }
}

// QKV GEMM (160 tiles) + idle-CU aux work (Wdense convert, RoPE table, alibi
// scale) on the remaining 96 blocks of a 256-block grid.
__global__ __launch_bounds__(512, 2) void gemm_qkv(
    const unsigned short* __restrict__ A, const unsigned short* __restrict__ Bm,
    float* __restrict__ C,
    const float* __restrict__ Wdense, unsigned short* __restrict__ WdenseB,
    const float* __restrict__ alibi, float* __restrict__ alibiS,
    float* __restrict__ cosT, float* __restrict__ sinT) {
  const int bid = blockIdx.x;                 // grid = 256
  const int wg  = (bid & 7) * 32 + (bid >> 3);
  if (wg < 160) {
    gemm256_core(A, HIDDIM, Bm, HIDDIM, C, QKVN,
                 (wg / 20) << 8, (wg % 20) << 8, 0, 64);
    return;
  }
  const int aid = wg - 160;                   // 0..95
  const int t = threadIdx.x;
  if (aid < 94) {                             // Wdense fp32 -> bf16
    const int n4 = HIDDIM * HIDDIM / 4;
    for (int i = aid * 512 + t; i < n4; i += 94 * 512) {
      float4 v = ((const float4*)Wdense)[i];
      ushort4 o;
      o.x = f2bf(v.x); o.y = f2bf(v.y); o.z = f2bf(v.z); o.w = f2bf(v.w);
      ((ushort4*)WdenseB)[i] = o;
    }
  } else if (aid == 94) {                     // RoPE cos/sin table
    for (int i = t; i < S_LEN * 32; i += 512) {
      int s = i >> 5, d = i & 31;
      float inv_freq = powf(10000.f, -(float)d * (1.f / 32.f));
      float ang = (float)s * inv_freq;
      cosT[i] = cosf(ang);
      sinT[i] = sinf(ang);
    }
  } else {                                    // alibi * INV_NORM
    const int n4 = 2 * NHEADS * S_LEN / 4;
    for (int i = t; i < n4; i += 512) {
      float4 v = ((const float4*)alibi)[i];
      v.x *= INV_NORM; v.y *= INV_NORM; v.z *= INV_NORM; v.w *= INV_NORM;
      ((float4*)alibiS)[i] = v;
    }
  }
}

// Dense GEMM, split-K=2 in one 256-block launch: block -> (tile, khalf),
// partials to Cp[khalf]; reduce_add sums into the final output.
__global__ __launch_bounds__(512, 2) void gemm_dense(
    const unsigned short* __restrict__ A, const unsigned short* __restrict__ Bm,
    float* __restrict__ Cp) {
  const int bid = blockIdx.x;                 // grid = 256
  const int wg  = (bid & 7) * 32 + (bid >> 3);
  const int khalf = wg >> 7, tile = wg & 127; // 128 tiles = 8M x 16N
  gemm256_core(A, HIDDIM, Bm, HIDDIM,
               Cp + (size_t)khalf * MTOK * HIDDIM, HIDDIM,
               (tile >> 4) << 8, (tile & 15) << 8, khalf * 2048, 32);
}

// ================================================================ attention
// 32x32 swapped-operand flash attention (verified round 2, unchanged).
__global__ __launch_bounds__(256, 2) void attn_fwd(
    const unsigned short* __restrict__ Qb,   // [B*NH, S, 64] bf16 (x INV_NORM)
    const unsigned short* __restrict__ Kb,   // [B*NKV, S, 64] bf16
    const unsigned short* __restrict__ Vt,   // [B*NKV, 64, S] bf16
    const float* __restrict__ alibiS,        // [B*NH, S] f32 (x INV_NORM)
    unsigned short* __restrict__ ctx) {
  __shared__ char lds[32768];                // [2 buf][ K 8KB | V 8KB ]

  const int qt  = 7 - blockIdx.x;            // longest-first dispatch
  const int bh  = blockIdx.y;
  const int b   = bh >> 6, h = bh & 63;
  const int kvh = b * NKVH + (h >> 3);
  const int qbase = qt * 128;
  const int nkt = 2 * qt + 2;

  const int t    = threadIdx.x;
  const int lane = t & 63;
  const int w    = t >> 6;
  const int l31  = lane & 31;
  const int hi   = lane >> 5;

  const unsigned short* Ksrc = Kb + (size_t)kvh * (S_LEN * HEADD);
  const unsigned short* Vsrc = Vt + (size_t)kvh * (HEADD * S_LEN);
  const float* al = alibiS + (size_t)bh * S_LEN;

  #define ASTG(buf, kt_) {                                                     \
    _Pragma("unroll") for (int i = 0; i < 2; ++i) {                            \
      int c = i * 256 + t; int row = c >> 3;                                   \
      int kb = ((c & 7) * 16) ^ ((row & 7) << 4);                              \
      gload16(Ksrc + ((size_t)((kt_) * 64 + row)) * HEADD + (kb >> 1),         \
              lds + (buf) * 16384 + c * 16);                                   \
      gload16(Vsrc + (size_t)row * S_LEN + (kt_) * 64 + (kb >> 1),             \
              lds + (buf) * 16384 + 8192 + c * 16);                            \
    } }

  const int qrow = qbase + w * 32 + l31;
  const unsigned short* Qr = Qb + ((size_t)bh * S_LEN + qrow) * HEADD;
  bf16x8 qF[4];
  #pragma unroll
  for (int ks = 0; ks < 4; ++ks)
    qF[ks] = *(const bf16x8*)(Qr + ks * 16 + hi * 8);

  f32x16 accO[2];
  #pragma unroll
  for (int di = 0; di < 2; ++di)
    #pragma unroll
    for (int r = 0; r < 16; ++r) accO[di][r] = 0.f;
  float mrun = -1e30f, lrun = 0.f;

  ASTG(0, 0);
  for (int kt = 0; kt < nkt; ++kt) {
    const int ktn = (kt + 1 < nkt) ? kt + 1 : kt;   // clamped re-stage
    ASTG((kt + 1) & 1, ktn);
    VMW(4);                                          // current buf complete
    BAR();
    const char* lK = lds + (kt & 1) * 16384;
    const char* lV = lK + 8192;

    float4 a4[2][4];
    #pragma unroll
    for (int blk = 0; blk < 2; ++blk)
      #pragma unroll
      for (int g = 0; g < 4; ++g)
        a4[blk][g] = *(const float4*)(al + kt * 64 + blk * 32 + 8 * g + 4 * hi);

    // ---- S^T = K Q^T : accS[blk] covers kv = blk*32.., q = l31
    f32x16 accS[2];
    #pragma unroll
    for (int blk = 0; blk < 2; ++blk)
      #pragma unroll
      for (int r = 0; r < 16; ++r) accS[blk][r] = 0.f;
    #pragma unroll
    for (int ks = 0; ks < 4; ++ks)
      #pragma unroll
      for (int blk = 0; blk < 2; ++blk) {
        int row = blk * 32 + l31;
        bf16x8 kF = *(const bf16x8*)(lK + row * 128 +
                     ((ks * 32 + hi * 16) ^ ((row & 7) << 4)));
        accS[blk] = __builtin_amdgcn_mfma_f32_32x32x16_bf16(kF, qF[ks], accS[blk], 0, 0, 0);
      }

    // ---- online softmax (lane-local row; partner lane holds other 32 kv)
    const bool domask = (kt >= 2 * qt);
    float mt = -1e30f;
    #pragma unroll
    for (int blk = 0; blk < 2; ++blk)
      #pragma unroll
      for (int r = 0; r < 16; ++r) {
        float x = accS[blk][r] + (&a4[blk][r >> 2].x)[r & 3];
        if (domask) {
          int kv = kt * 64 + blk * 32 + 8 * (r >> 2) + 4 * hi + (r & 3);
          x = (kv > qrow) ? -1e30f : x;
        }
        accS[blk][r] = x;
        mt = fmaxf(mt, x);
      }
    mt = fmaxf(mt, __shfl_xor(mt, 32));
    if (!__all(mt - mrun <= 8.0f)) {       // T13 defer-max
      float mn = fmaxf(mrun, mt);
      float sc = __expf(mrun - mn);
      lrun *= sc;
      #pragma unroll
      for (int di = 0; di < 2; ++di)
        #pragma unroll
        for (int r = 0; r < 16; ++r) accO[di][r] *= sc;
      mrun = mn;
    }
    float s_own = 0.f;
    #pragma unroll
    for (int blk = 0; blk < 2; ++blk)
      #pragma unroll
      for (int r = 0; r < 16; ++r) {
        float p = __expf(accS[blk][r] - mrun);
        accS[blk][r] = p;
        s_own += p;
      }
    lrun += s_own + __shfl_xor(s_own, 32);

    // ---- pack P to bf16 pairs: W[blk][g][h] = (p[4g+2h], p[4g+2h+1])
    unsigned W[2][4][2];
    #pragma unroll
    for (int blk = 0; blk < 2; ++blk)
      #pragma unroll
      for (int g = 0; g < 4; ++g)
        #pragma unroll
        for (int hh = 0; hh < 2; ++hh) {
          unsigned lo = (unsigned)__builtin_bit_cast(unsigned short,
                          (__bf16)accS[blk][g * 4 + 2 * hh]);
          unsigned hi16 = (unsigned)__builtin_bit_cast(unsigned short,
                          (__bf16)accS[blk][g * 4 + 2 * hh + 1]);
          W[blk][g][hh] = lo | (hi16 << 16);
        }

    // ---- exchange to PV B-frags uB[q16]: [q=l31][k_kv = q16*16 + hi*8 + j]
    bf16x8 uB[4];
    #pragma unroll
    for (int q16 = 0; q16 < 4; ++q16) {
      const int blk = q16 >> 1, g0 = 2 * (q16 & 1);
      unsigned A0 = W[blk][g0][0],     A1 = W[blk][g0][1];
      unsigned B0 = W[blk][g0 + 1][0], B1 = W[blk][g0 + 1][1];
      unsigned own0 = hi ? B0 : A0, own1 = hi ? B1 : A1;
      unsigned sw0  = hi ? A0 : B0, sw1  = hi ? A1 : B1;
      unsigned X0 = (unsigned)__shfl_xor((int)sw0, 32);
      unsigned X1 = (unsigned)__shfl_xor((int)sw1, 32);
      union { unsigned u[4]; bf16x8 v; } U;
      U.u[0] = hi ? X0 : own0;
      U.u[1] = hi ? X1 : own1;
      U.u[2] = hi ? own0 : X0;
      U.u[3] = hi ? own1 : X1;
      uB[q16] = U.v;
    }

    // ---- O^T += V^T P^T : accO[di] covers d = di*32.., q = l31
    #pragma unroll
    for (int q16 = 0; q16 < 4; ++q16)
      #pragma unroll
      for (int di = 0; di < 2; ++di) {
        int row = di * 32 + l31;
        bf16x8 vF = *(const bf16x8*)(lV + row * 128 +
                     ((q16 * 32 + hi * 16) ^ ((row & 7) << 4)));
        accO[di] = __builtin_amdgcn_mfma_f32_32x32x16_bf16(vF, uB[q16], accO[di], 0, 0, 0);
      }
    BAR();   // all reads of this buf done before it is restaged
  }
  VMW(0);    // drain clamped re-stage DMA before exit

  // ---- epilogue: ctx[b, q, h*64 + d], d = di*32 + 8g + 4hi + r
  float inv_l = 1.0f / lrun;
  #pragma unroll
  for (int di = 0; di < 2; ++di)
    #pragma unroll
    for (int g = 0; g < 4; ++g) {
      ushort4 o;
      o.x = __builtin_bit_cast(unsigned short, (__bf16)(accO[di][g * 4 + 0] * inv_l));
      o.y = __builtin_bit_cast(unsigned short, (__bf16)(accO[di][g * 4 + 1] * inv_l));
      o.z = __builtin_bit_cast(unsigned short, (__bf16)(accO[di][g * 4 + 2] * inv_l));
      o.w = __builtin_bit_cast(unsigned short, (__bf16)(accO[di][g * 4 + 3] * inv_l));
      int d = di * 32 + 8 * g + 4 * hi;
      *(ushort4*)(ctx + ((size_t)b * S_LEN + qrow) * (NHEADS * HEADD) + h * 64 + d) = o;
    }
  #undef ASTG
}

// ---------------------------------------------------------------- launch
extern "C" void kernel_launch(void* const* d_in, const int* in_sizes, int n_in,
                              void* d_out, int out_size, void* d_ws, size_t ws_size,
                              hipStream_t stream) {
  const float* hidden = (const float*)d_in[0];
  const float* alibi  = (const float*)d_in[1];
  // d_in[2] = attention_mask: deterministically causal triu(k=1) -> analytic
  const float* Wqkv   = (const float*)d_in[3];
  const float* Wdense = (const float*)d_in[4];
  float* out = (float*)d_out;

  char* p = (char*)d_ws;
  auto alloc = [&](size_t bytes) {
    char* r = p; p += (bytes + 255) & ~(size_t)255; return r;
  };
  // Order matters: [hiddenB, WqkvB, fused] form a contiguous dead-by-dense
  // region that the split-K partial buffers alias.
  unsigned short* WdenseB = (unsigned short*)alloc((size_t)HIDDIM * HIDDIM * 2);
  unsigned short* hiddenB = (unsigned short*)alloc((size_t)MTOK * HIDDIM * 2);
  unsigned short* WqkvB   = (unsigned short*)alloc((size_t)QKVN * HIDDIM * 2);
  float*          fused   = (float*)alloc((size_t)MTOK * QKVN * 4);
  unsigned short* Qb      = (unsigned short*)alloc((size_t)2 * NHEADS * S_LEN * HEADD * 2);
  unsigned short* Kb      = (unsigned short*)alloc((size_t)2 * NKVH * S_LEN * HEADD * 2);
  unsigned short* Vt      = (unsigned short*)alloc((size_t)2 * NKVH * HEADD * S_LEN * 2);
  unsigned short* ctxB    = (unsigned short*)alloc((size_t)MTOK * HIDDIM * 2);
  float*          cosT    = (float*)alloc((size_t)S_LEN * 32 * 4);
  float*          sinT    = (float*)alloc((size_t)S_LEN * 32 * 4);
  float*          alibiS  = (float*)alloc((size_t)2 * NHEADS * S_LEN * 4);
  // Split-K partials (2 x 2048x4096 fp32 = 67 MB) alias hiddenB..fused
  // (16.8+41.9+41.9 = 100.6 MB), all dead before gemm_dense runs.
  float* Cp = (float*)hiddenB;

  cvt_bf16<<<1024, 256, 0, stream>>>(hidden, hiddenB, MTOK * HIDDIM / 4);
  cvt_bf16<<<2048, 256, 0, stream>>>(Wqkv,   WqkvB,   QKVN * HIDDIM / 4);

  // QKV GEMM (160 tiles) + aux work (Wdense cvt, rope table, alibi scale)
  gemm_qkv<<<256, 512, 0, stream>>>(hiddenB, WqkvB, fused,
                                    Wdense, WdenseB, alibi, alibiS, cosT, sinT);

  rope_qk<<<(MTOK * NKVH * 9 * 32) / 256, 256, 0, stream>>>(fused, cosT, sinT, Qb, Kb);
  v_transpose<<<dim3(S_LEN / 64, 2 * NKVH), 256, 0, stream>>>(fused, Vt);

  attn_fwd<<<dim3(S_LEN / 128, 2 * NHEADS), 256, 0, stream>>>(Qb, Kb, Vt, alibiS, ctxB);

  gemm_dense<<<256, 512, 0, stream>>>(ctxB, WdenseB, Cp);
  reduce_add<<<(MTOK * HIDDIM / 4) / 256, 256, 0, stream>>>(
      Cp, Cp + (size_t)MTOK * HIDDIM, out, MTOK * HIDDIM / 4);
}